// Round 23
// baseline (18.056 us; speedup 1.0000x reference)
//
#include <hip/hip_runtime.h>
#include <math.h>

typedef short bf16x8 __attribute__((ext_vector_type(8)));
typedef float f32x16 __attribute__((ext_vector_type(16)));
typedef unsigned int u32x4 __attribute__((ext_vector_type(4)));

#define B 16
#define N 4096
#define K 4096
#define OBJ_ELEMS (8*512*3)        // 12288 per batch
#define OBJ_VEC4  (OBJ_ELEMS/4)    // 3072 float4 per batch
#define NSEG 32
#define NCHUNK (N/NSEG)            // 128 adv rows per block (2 groups x 64)
#define BLK 512                    // 8 waves: 2 adv-groups x 4 K-quarters
#define OBJ_V4_PER_BLK (OBJ_VEC4/NSEG) // 96 float4 per block
#define CD_W 0.2f
#define EPS_F 1e-7f

// ws layout (floats): csum[B*NSEG] @0, lsq[B*NSEG] @512
#define CS_OFF 0
#define LS_OFF (B*NSEG)

#define MIN3(a,b,c) fminf(fminf((a),(b)),(c))

__device__ __forceinline__ unsigned int cvt_pk_bf16(float lo, float hi) {
    unsigned int r;
    asm volatile("v_cvt_pk_bf16_f32 %0, %1, %2" : "=v"(r) : "v"(lo), "v"(hi));
    return r;
}

// tree-min of 32 MFMA outputs into m (16 v_min3, depth 4)
__device__ __forceinline__ float tree32(const f32x16& c0, const f32x16& c1,
                                        float m) {
    #define V(i) ((i) < 16 ? c0[(i)] : c1[(i)-16])
    float g0 = MIN3(V(0),  V(1),  V(2));
    float g1 = MIN3(V(3),  V(4),  V(5));
    float g2 = MIN3(V(6),  V(7),  V(8));
    float g3 = MIN3(V(9),  V(10), V(11));
    float g4 = MIN3(V(12), V(13), V(14));
    float g5 = MIN3(V(15), V(16), V(17));
    float g6 = MIN3(V(18), V(19), V(20));
    float g7 = MIN3(V(21), V(22), V(23));
    float g8 = MIN3(V(24), V(25), V(26));
    float g9 = MIN3(V(27), V(28), V(29));
    float h0 = MIN3(g0, g1, g2);
    float h1 = MIN3(g3, g4, g5);
    float h2 = MIN3(g6, g7, g8);
    float h3 = MIN3(g9, V(30), V(31));
    return MIN3(MIN3(h0, h1, h2), h3, m);
    #undef V
}

__global__ __launch_bounds__(BLK, 4) void chamfer_mfma_kernel(
    const float* __restrict__ adv, const float* __restrict__ ori,
    const float* __restrict__ adv_obj, const float* __restrict__ ori_obj,
    float* __restrict__ csum, float* __restrict__ lsq)
{
    __shared__ uint2 slds[K];              // 32 KB: ori bf16 {-2x,-2y | -2z,o2}
    __shared__ float rowmin[8][64];        // per-wave per-adv-col min (+a2)
    __shared__ float red_c[2], red_l[2];

    const int nseg = blockIdx.x;
    const int b    = blockIdx.y;
    const int tid  = threadIdx.x;
    const int wid  = tid >> 6;
    const int lane = tid & 63;
    const int col  = lane & 31;
    const int hi   = lane >> 5;
    const int rg   = wid & 1;              // adv group (64 rows each)
    const int kh   = wid >> 1;             // K quarter (1024 ori points each)

    // --- stage + convert ori: 6 float4 loads -> 8 packed points per thread ---
    {
        const float4* src =
            reinterpret_cast<const float4*>(ori + (size_t)(b*K + tid*8)*3);
        float4 f0 = src[0], f1 = src[1], f2 = src[2];
        float4 f3 = src[3], f4 = src[4], f5 = src[5];
        float xs[8], ys[8], zs[8];
        xs[0]=f0.x; ys[0]=f0.y; zs[0]=f0.z;
        xs[1]=f0.w; ys[1]=f1.x; zs[1]=f1.y;
        xs[2]=f1.z; ys[2]=f1.w; zs[2]=f2.x;
        xs[3]=f2.y; ys[3]=f2.z; zs[3]=f2.w;
        xs[4]=f3.x; ys[4]=f3.y; zs[4]=f3.z;
        xs[5]=f3.w; ys[5]=f4.x; zs[5]=f4.y;
        xs[6]=f4.z; ys[6]=f4.w; zs[6]=f5.x;
        xs[7]=f5.y; ys[7]=f5.z; zs[7]=f5.w;
        #pragma unroll
        for (int j = 0; j < 8; ++j) {
            float x = xs[j], y = ys[j], z = zs[j];
            float o2 = x*x + y*y + z*z;
            uint2 e;
            e.x = cvt_pk_bf16(-2.f*x, -2.f*y);
            e.y = cvt_pk_bf16(-2.f*z, o2);
            slds[tid*8 + j] = e;
        }
    }

    // --- two B fragments (adv): lane's cols = rg*64+col and rg*64+32+col ---
    const int n0i = nseg*NCHUNK + rg*64 + col;
    const float* ap0 = adv + (size_t)(b*N + n0i)*3;
    const float* ap1 = ap0 + 32*3;
    float ax0 = ap0[0], ay0 = ap0[1], az0 = ap0[2];
    float ax1 = ap1[0], ay1 = ap1[1], az1 = ap1[2];
    float a2_0 = ax0*ax0 + ay0*ay0 + az0*az0;
    float a2_1 = ax1*ax1 + ay1*ay1 + az1*az1;
    unsigned int b00 = 0u, b01 = 0u, b10 = 0u, b11 = 0u;
    if (hi == 0) {
        b00 = cvt_pk_bf16(ax0, ay0);
        b01 = cvt_pk_bf16(az0, 1.0f);
        b10 = cvt_pk_bf16(ax1, ay1);
        b11 = cvt_pk_bf16(az1, 1.0f);
    }
    u32x4 bw0 = {b00, b01, 0u, 0u};
    u32x4 bw1 = {b10, b11, 0u, 0u};
    bf16x8 bfrag0 = __builtin_bit_cast(bf16x8, bw0);
    bf16x8 bfrag1 = __builtin_bit_cast(bf16x8, bw1);

    __syncthreads();

    // --- main loop: depth-1 pipeline + setprio(1) around MFMA issue groups
    //     (waves drift out of phase; prio keeps the matrix pipe fed) ---
    float m0 = INFINITY, m1 = INFINITY;
    const f32x16 zc = {0,0,0,0, 0,0,0,0, 0,0,0,0, 0,0,0,0};
    const float4* s4 = reinterpret_cast<const float4*>(slds);  // 2 pts/float4
    const int base = kh*16;

    f32x16 c0, c1, c2, c3;
    {
        float4 q = s4[base*32 + col];
        u32x4 uu = __builtin_bit_cast(u32x4, q);
        u32x4 wa = {uu.x, uu.y, 0u, 0u};
        u32x4 wb = {uu.z, uu.w, 0u, 0u};
        bf16x8 ta = __builtin_bit_cast(bf16x8, wa);
        bf16x8 tb = __builtin_bit_cast(bf16x8, wb);
        __builtin_amdgcn_s_setprio(1);
        c0 = __builtin_amdgcn_mfma_f32_32x32x16_bf16(ta, bfrag0, zc, 0,0,0);
        c1 = __builtin_amdgcn_mfma_f32_32x32x16_bf16(tb, bfrag0, zc, 0,0,0);
        c2 = __builtin_amdgcn_mfma_f32_32x32x16_bf16(ta, bfrag1, zc, 0,0,0);
        c3 = __builtin_amdgcn_mfma_f32_32x32x16_bf16(tb, bfrag1, zc, 0,0,0);
        __builtin_amdgcn_s_setprio(0);
    }
    #pragma unroll
    for (int t = 1; t < 16; ++t) {
        float4 q = s4[(base + t)*32 + col];
        u32x4 uu = __builtin_bit_cast(u32x4, q);
        u32x4 wa = {uu.x, uu.y, 0u, 0u};
        u32x4 wb = {uu.z, uu.w, 0u, 0u};
        bf16x8 ta = __builtin_bit_cast(bf16x8, wa);
        bf16x8 tb = __builtin_bit_cast(bf16x8, wb);
        __builtin_amdgcn_s_setprio(1);
        f32x16 n0 = __builtin_amdgcn_mfma_f32_32x32x16_bf16(ta, bfrag0, zc, 0,0,0);
        f32x16 n1 = __builtin_amdgcn_mfma_f32_32x32x16_bf16(tb, bfrag0, zc, 0,0,0);
        __builtin_amdgcn_s_setprio(0);
        m0 = tree32(c0, c1, m0);   // fold prev pair A while next MFMAs run
        __builtin_amdgcn_s_setprio(1);
        f32x16 n2 = __builtin_amdgcn_mfma_f32_32x32x16_bf16(ta, bfrag1, zc, 0,0,0);
        f32x16 n3 = __builtin_amdgcn_mfma_f32_32x32x16_bf16(tb, bfrag1, zc, 0,0,0);
        __builtin_amdgcn_s_setprio(0);
        m1 = tree32(c2, c3, m1);   // fold prev pair B
        c0 = n0; c1 = n1; c2 = n2; c3 = n3;
    }
    m0 = tree32(c0, c1, m0);
    m1 = tree32(c2, c3, m1);

    // --- lane-local finish: fold hi/lo halves, add a2 ---
    m0 = fminf(m0, __shfl_xor(m0, 32)) + a2_0;
    m1 = fminf(m1, __shfl_xor(m1, 32)) + a2_1;
    if (hi == 0) {
        rowmin[wid][col]      = m0;
        rowmin[wid][32 + col] = m1;
    }
    __syncthreads();

    // --- epilogue: combine 4 K-quarters (waves 0-1); waves 2-3 fold obj-L2 ---
    float s = 0.f;
    if (wid < 2) {             // 128 threads: one adv row each
        int row = tid;         // 0..127
        int rg2 = row >> 6, ri = row & 63;
        s = fminf(fminf(rowmin[rg2][ri],     rowmin[2 + rg2][ri]),
                  fminf(rowmin[4 + rg2][ri], rowmin[6 + rg2][ri]));
    } else if (wid < 4) {      // 96 of 128 threads: obj-L2 slice
        int li = (wid - 2)*64 + lane;
        if (li < OBJ_V4_PER_BLK) {
            int idx = b*OBJ_VEC4 + nseg*OBJ_V4_PER_BLK + li;
            float4 a = reinterpret_cast<const float4*>(adv_obj)[idx];
            float4 o = reinterpret_cast<const float4*>(ori_obj)[idx];
            float dx = a.x - o.x, dy = a.y - o.y, dz = a.z - o.z, dw = a.w - o.w;
            s = dx*dx + dy*dy + dz*dz + dw*dw;
        }
    }
    #pragma unroll
    for (int off = 32; off; off >>= 1) s += __shfl_down(s, off);
    if (lane == 0) {
        if (wid < 2)       red_c[wid]     = s;
        else if (wid < 4)  red_l[wid - 2] = s;
    }
    __syncthreads();
    if (tid == 0) csum[b*NSEG + nseg] = red_c[0] + red_c[1];
    if (tid == 1) lsq [b*NSEG + nseg] = red_l[0] + red_l[1];
}

__global__ __launch_bounds__(256) void final_kernel(
    const float* __restrict__ csum, const float* __restrict__ lsq,
    const float* __restrict__ w, float* __restrict__ out)
{
    const int tid = threadIdx.x;           // 256 threads, 2 partials each
    float c = csum[2*tid] + csum[2*tid + 1];
    float l = lsq [2*tid] + lsq [2*tid + 1];
    // 16 partial-pairs per batch live in one 16-lane group
    #pragma unroll
    for (int off = 8; off; off >>= 1) {
        c += __shfl_down(c, off, 16);
        l += __shfl_down(l, off, 16);
    }
    __shared__ float sc[B], sl[B];
    int bb = tid >> 4;
    if ((tid & 15) == 0) { sc[bb] = c; sl[bb] = l; }
    __syncthreads();
    if (tid < 64) {
        float cc = 0.f, ll = 0.f;
        if (tid < B) {
            float wt = w[tid];
            cc = (sc[tid] / (float)N) * wt;
            ll = sqrtf(sl[tid] + EPS_F) * wt;
        }
        #pragma unroll
        for (int off = 8; off; off >>= 1) {
            cc += __shfl_down(cc, off);
            ll += __shfl_down(ll, off);
        }
        if (tid == 0) out[0] = ll / (float)B + CD_W * (cc / (float)B);
    }
}

extern "C" void kernel_launch(void* const* d_in, const int* in_sizes, int n_in,
                              void* d_out, int out_size, void* d_ws, size_t ws_size,
                              hipStream_t stream)
{
    const float* adv_pc  = (const float*)d_in[0];
    const float* ori_pc  = (const float*)d_in[1];
    const float* adv_obj = (const float*)d_in[2];
    const float* ori_obj = (const float*)d_in[3];
    const float* weights = (const float*)d_in[4];
    float* out = (float*)d_out;
    float* ws  = (float*)d_ws;

    float* csum = ws + CS_OFF;
    float* lsq  = ws + LS_OFF;

    // 1) fused MFMA chamfer (pipelined + setprio around MFMA groups):
    //    grid = (NSEG, B) = 512 blocks of 512
    chamfer_mfma_kernel<<<dim3(NSEG, B), dim3(BLK), 0, stream>>>(
        adv_pc, ori_pc, adv_obj, ori_obj, csum, lsq);

    // 2) weighted final combine (1 block)
    final_kernel<<<dim3(1), dim3(256), 0, stream>>>(csum, lsq, weights, out);
}

// Round 24
// 16.321 us; speedup vs baseline: 1.1063x; 1.1063x over previous
//
#include <hip/hip_runtime.h>
#include <math.h>

typedef short bf16x8 __attribute__((ext_vector_type(8)));
typedef float f32x16 __attribute__((ext_vector_type(16)));
typedef unsigned int u32x4 __attribute__((ext_vector_type(4)));

#define B 16
#define N 4096
#define K 4096
#define OBJ_ELEMS (8*512*3)        // 12288 per batch
#define OBJ_VEC4  (OBJ_ELEMS/4)    // 3072 float4 per batch
#define NSEG 32
#define NCHUNK (N/NSEG)            // 128 adv rows per block (2 groups x 64)
#define BLK 512                    // 8 waves: 2 adv-groups x 4 K-quarters
#define OBJ_V4_PER_BLK (OBJ_VEC4/NSEG) // 96 float4 per block
#define CD_W 0.2f
#define EPS_F 1e-7f

// ws layout (floats): csum[B*NSEG] @0, lsq[B*NSEG] @512
#define CS_OFF 0
#define LS_OFF (B*NSEG)

#define MIN3(a,b,c) fminf(fminf((a),(b)),(c))

__device__ __forceinline__ unsigned int cvt_pk_bf16(float lo, float hi) {
    unsigned int r;
    asm volatile("v_cvt_pk_bf16_f32 %0, %1, %2" : "=v"(r) : "v"(lo), "v"(hi));
    return r;
}

// tree-min of 32 MFMA outputs into m (16 v_min3, depth 4)
__device__ __forceinline__ float tree32(const f32x16& c0, const f32x16& c1,
                                        float m) {
    #define V(i) ((i) < 16 ? c0[(i)] : c1[(i)-16])
    float g0 = MIN3(V(0),  V(1),  V(2));
    float g1 = MIN3(V(3),  V(4),  V(5));
    float g2 = MIN3(V(6),  V(7),  V(8));
    float g3 = MIN3(V(9),  V(10), V(11));
    float g4 = MIN3(V(12), V(13), V(14));
    float g5 = MIN3(V(15), V(16), V(17));
    float g6 = MIN3(V(18), V(19), V(20));
    float g7 = MIN3(V(21), V(22), V(23));
    float g8 = MIN3(V(24), V(25), V(26));
    float g9 = MIN3(V(27), V(28), V(29));
    float h0 = MIN3(g0, g1, g2);
    float h1 = MIN3(g3, g4, g5);
    float h2 = MIN3(g6, g7, g8);
    float h3 = MIN3(g9, V(30), V(31));
    return MIN3(MIN3(h0, h1, h2), h3, m);
    #undef V
}

__global__ __launch_bounds__(BLK, 4) void chamfer_mfma_kernel(
    const float* __restrict__ adv, const float* __restrict__ ori,
    const float* __restrict__ adv_obj, const float* __restrict__ ori_obj,
    float* __restrict__ csum, float* __restrict__ lsq)
{
    __shared__ uint2 slds[K];              // 32 KB: ori bf16 {-2x,-2y | -2z,o2}
    __shared__ float rowmin[8][64];        // per-wave per-adv-col min (+a2)
    __shared__ float red_c[2], red_l[2];

    const int nseg = blockIdx.x;
    const int b    = blockIdx.y;
    const int tid  = threadIdx.x;
    const int wid  = tid >> 6;
    const int lane = tid & 63;
    const int col  = lane & 31;
    const int hi   = lane >> 5;
    const int rg   = wid & 1;              // adv group (64 rows each)
    const int kh   = wid >> 1;             // K quarter (1024 ori points each)

    // --- stage + convert ori: 6 float4 loads -> 8 packed points per thread ---
    {
        const float4* src =
            reinterpret_cast<const float4*>(ori + (size_t)(b*K + tid*8)*3);
        float4 f0 = src[0], f1 = src[1], f2 = src[2];
        float4 f3 = src[3], f4 = src[4], f5 = src[5];
        float xs[8], ys[8], zs[8];
        xs[0]=f0.x; ys[0]=f0.y; zs[0]=f0.z;
        xs[1]=f0.w; ys[1]=f1.x; zs[1]=f1.y;
        xs[2]=f1.z; ys[2]=f1.w; zs[2]=f2.x;
        xs[3]=f2.y; ys[3]=f2.z; zs[3]=f2.w;
        xs[4]=f3.x; ys[4]=f3.y; zs[4]=f3.z;
        xs[5]=f3.w; ys[5]=f4.x; zs[5]=f4.y;
        xs[6]=f4.z; ys[6]=f4.w; zs[6]=f5.x;
        xs[7]=f5.y; ys[7]=f5.z; zs[7]=f5.w;
        #pragma unroll
        for (int j = 0; j < 8; ++j) {
            float x = xs[j], y = ys[j], z = zs[j];
            float o2 = x*x + y*y + z*z;
            uint2 e;
            e.x = cvt_pk_bf16(-2.f*x, -2.f*y);
            e.y = cvt_pk_bf16(-2.f*z, o2);
            slds[tid*8 + j] = e;
        }
    }

    // --- two B fragments (adv): lane's cols = rg*64+col and rg*64+32+col ---
    const int n0 = nseg*NCHUNK + rg*64 + col;
    const float* ap0 = adv + (size_t)(b*N + n0)*3;
    const float* ap1 = ap0 + 32*3;
    float ax0 = ap0[0], ay0 = ap0[1], az0 = ap0[2];
    float ax1 = ap1[0], ay1 = ap1[1], az1 = ap1[2];
    float a2_0 = ax0*ax0 + ay0*ay0 + az0*az0;
    float a2_1 = ax1*ax1 + ay1*ay1 + az1*az1;
    unsigned int b00 = 0u, b01 = 0u, b10 = 0u, b11 = 0u;
    if (hi == 0) {
        b00 = cvt_pk_bf16(ax0, ay0);
        b01 = cvt_pk_bf16(az0, 1.0f);
        b10 = cvt_pk_bf16(ax1, ay1);
        b11 = cvt_pk_bf16(az1, 1.0f);
    }
    u32x4 bw0 = {b00, b01, 0u, 0u};
    u32x4 bw1 = {b10, b11, 0u, 0u};
    bf16x8 bfrag0 = __builtin_bit_cast(bf16x8, bw0);
    bf16x8 bfrag1 = __builtin_bit_cast(bf16x8, bw1);

    __syncthreads();

    // --- main loop: depth-1 software pipeline: issue iter t+1's MFMAs
    //     before folding iter t's outputs (MFMA pipe busy during min-trees) ---
    float m0 = INFINITY, m1 = INFINITY;
    const f32x16 zc = {0,0,0,0, 0,0,0,0, 0,0,0,0, 0,0,0,0};
    const float4* s4 = reinterpret_cast<const float4*>(slds);  // 2 pts/float4
    const int base = kh*16;

    f32x16 c0, c1, c2, c3;
    {
        float4 q = s4[base*32 + col];
        u32x4 uu = __builtin_bit_cast(u32x4, q);
        u32x4 wa = {uu.x, uu.y, 0u, 0u};
        u32x4 wb = {uu.z, uu.w, 0u, 0u};
        bf16x8 ta = __builtin_bit_cast(bf16x8, wa);
        bf16x8 tb = __builtin_bit_cast(bf16x8, wb);
        c0 = __builtin_amdgcn_mfma_f32_32x32x16_bf16(ta, bfrag0, zc, 0,0,0);
        c1 = __builtin_amdgcn_mfma_f32_32x32x16_bf16(tb, bfrag0, zc, 0,0,0);
        c2 = __builtin_amdgcn_mfma_f32_32x32x16_bf16(ta, bfrag1, zc, 0,0,0);
        c3 = __builtin_amdgcn_mfma_f32_32x32x16_bf16(tb, bfrag1, zc, 0,0,0);
    }
    #pragma unroll
    for (int t = 1; t < 16; ++t) {
        float4 q = s4[(base + t)*32 + col];
        u32x4 uu = __builtin_bit_cast(u32x4, q);
        u32x4 wa = {uu.x, uu.y, 0u, 0u};
        u32x4 wb = {uu.z, uu.w, 0u, 0u};
        bf16x8 ta = __builtin_bit_cast(bf16x8, wa);
        bf16x8 tb = __builtin_bit_cast(bf16x8, wb);
        f32x16 n0 = __builtin_amdgcn_mfma_f32_32x32x16_bf16(ta, bfrag0, zc, 0,0,0);
        f32x16 n1 = __builtin_amdgcn_mfma_f32_32x32x16_bf16(tb, bfrag0, zc, 0,0,0);
        m0 = tree32(c0, c1, m0);   // fold prev pair A while next MFMAs run
        f32x16 n2 = __builtin_amdgcn_mfma_f32_32x32x16_bf16(ta, bfrag1, zc, 0,0,0);
        f32x16 n3 = __builtin_amdgcn_mfma_f32_32x32x16_bf16(tb, bfrag1, zc, 0,0,0);
        m1 = tree32(c2, c3, m1);   // fold prev pair B
        c0 = n0; c1 = n1; c2 = n2; c3 = n3;
    }
    m0 = tree32(c0, c1, m0);
    m1 = tree32(c2, c3, m1);

    // --- lane-local finish: fold hi/lo halves, add a2 ---
    m0 = fminf(m0, __shfl_xor(m0, 32)) + a2_0;
    m1 = fminf(m1, __shfl_xor(m1, 32)) + a2_1;
    if (hi == 0) {
        rowmin[wid][col]      = m0;
        rowmin[wid][32 + col] = m1;
    }
    __syncthreads();

    // --- epilogue: combine 4 K-quarters (waves 0-1); waves 2-3 fold obj-L2 ---
    float s = 0.f;
    if (wid < 2) {             // 128 threads: one adv row each
        int row = tid;         // 0..127
        int rg2 = row >> 6, ri = row & 63;
        s = fminf(fminf(rowmin[rg2][ri],     rowmin[2 + rg2][ri]),
                  fminf(rowmin[4 + rg2][ri], rowmin[6 + rg2][ri]));
    } else if (wid < 4) {      // 96 of 128 threads: obj-L2 slice
        int li = (wid - 2)*64 + lane;
        if (li < OBJ_V4_PER_BLK) {
            int idx = b*OBJ_VEC4 + nseg*OBJ_V4_PER_BLK + li;
            float4 a = reinterpret_cast<const float4*>(adv_obj)[idx];
            float4 o = reinterpret_cast<const float4*>(ori_obj)[idx];
            float dx = a.x - o.x, dy = a.y - o.y, dz = a.z - o.z, dw = a.w - o.w;
            s = dx*dx + dy*dy + dz*dz + dw*dw;
        }
    }
    #pragma unroll
    for (int off = 32; off; off >>= 1) s += __shfl_down(s, off);
    if (lane == 0) {
        if (wid < 2)       red_c[wid]     = s;
        else if (wid < 4)  red_l[wid - 2] = s;
    }
    __syncthreads();
    if (tid == 0) csum[b*NSEG + nseg] = red_c[0] + red_c[1];
    if (tid == 1) lsq [b*NSEG + nseg] = red_l[0] + red_l[1];
}

__global__ __launch_bounds__(256) void final_kernel(
    const float* __restrict__ csum, const float* __restrict__ lsq,
    const float* __restrict__ w, float* __restrict__ out)
{
    const int tid = threadIdx.x;           // 256 threads, 2 partials each
    float c = csum[2*tid] + csum[2*tid + 1];
    float l = lsq [2*tid] + lsq [2*tid + 1];
    // 16 partial-pairs per batch live in one 16-lane group
    #pragma unroll
    for (int off = 8; off; off >>= 1) {
        c += __shfl_down(c, off, 16);
        l += __shfl_down(l, off, 16);
    }
    __shared__ float sc[B], sl[B];
    int bb = tid >> 4;
    if ((tid & 15) == 0) { sc[bb] = c; sl[bb] = l; }
    __syncthreads();
    if (tid < 64) {
        float cc = 0.f, ll = 0.f;
        if (tid < B) {
            float wt = w[tid];
            cc = (sc[tid] / (float)N) * wt;
            ll = sqrtf(sl[tid] + EPS_F) * wt;
        }
        #pragma unroll
        for (int off = 8; off; off >>= 1) {
            cc += __shfl_down(cc, off);
            ll += __shfl_down(ll, off);
        }
        if (tid == 0) out[0] = ll / (float)B + CD_W * (cc / (float)B);
    }
}

extern "C" void kernel_launch(void* const* d_in, const int* in_sizes, int n_in,
                              void* d_out, int out_size, void* d_ws, size_t ws_size,
                              hipStream_t stream)
{
    const float* adv_pc  = (const float*)d_in[0];
    const float* ori_pc  = (const float*)d_in[1];
    const float* adv_obj = (const float*)d_in[2];
    const float* ori_obj = (const float*)d_in[3];
    const float* weights = (const float*)d_in[4];
    float* out = (float*)d_out;
    float* ws  = (float*)d_ws;

    float* csum = ws + CS_OFF;
    float* lsq  = ws + LS_OFF;

    // 1) fused MFMA chamfer (software-pipelined MFMA || min-tree):
    //    grid = (NSEG, B) = 512 blocks of 512
    chamfer_mfma_kernel<<<dim3(NSEG, B), dim3(BLK), 0, stream>>>(
        adv_pc, ori_pc, adv_obj, ori_obj, csum, lsq);

    // 2) weighted final combine (1 block)
    final_kernel<<<dim3(1), dim3(256), 0, stream>>>(csum, lsq, weights, out);
}